// Round 1
// baseline (1719.100 us; speedup 1.0000x reference)
//
#include <hip/hip_runtime.h>
#include <hip/hip_bf16.h>

// ---------------------------------------------------------------------------
// LatentActionGen v3: x = relu(s0@W0 + s1@W1 + b); flat = x@Wf + bf; VQ.
// v2 (351 us vq_main) was barrier-drain bound: 2-phase LDS staging forces
// s_waitcnt vmcnt(0) before every s_barrier -> one exposed HBM round trip
// per chunk (6560 cyc/step vs 3200 roofline).
// v3: BARRIER-FREE main GEMM. No LDS, no __syncthreads. Each wave owns
// 32 rows x 128 cols (2 row-frags, acc 64 VGPR) and reads B fragments
// directly from L2-resident bpack into registers (4 GiB L2 traffic ~116us,
// under the 171us HBM A-floor). A: nt loads, register double-buffer, issued
// one chunk (~800 cyc) ahead. B: two half-chunk register buffers, issued
// half a chunk ahead. Compiler emits counted vmcnt -> loads stay in flight
// across the whole K loop. 512 blocks x 256 thr, ~180 VGPR, 2 blocks/CU.
// Numerics identical to v2 (same 3-term split, same accumulation order).
// ---------------------------------------------------------------------------

typedef __bf16 bf16x8 __attribute__((ext_vector_type(8)));
typedef float  floatx4 __attribute__((ext_vector_type(4)));

#define NROWS  32768
#define DIM    4096
#define HID    128
#define NCODE  30
#define NCHUNK_TOT 256          // 8192 k / 32
#define NCHUNK_SL  128          // per K-slice (slice 0 = s0@W0, slice 1 = s1@W1)

// output layout: z[N*4], loss[N], perp[1], idx[N]
#define Z_OFF    0
#define LOSS_OFF (NROWS * 4)
#define PERP_OFF (LOSS_OFF + NROWS)
#define IDX_OFF  (PERP_OFF + 1)

// workspace layout
#define HIST_OFF_B   0                      // 256 B
#define BPACK_OFF_B  256                    // 4 MiB packed weights
#define PART_OFF_B   (8u * 1024 * 1024)     // 2 x 16 MiB fp32 partials

// ---------------------------------------------------------------------------
// Pack W0|W1 as bf16 hi/lo in B-fragment order (unchanged; verified).
// chunk c (16KB = 8192 bf16): [hi: t*1024B + lane*16][lo: +8192B]
// frag lane l holds B[k=8*(l>>4)+j][n=16t+(l&15)]
// ---------------------------------------------------------------------------
__global__ __launch_bounds__(256) void vq_prep_pack(
    const float* __restrict__ W0, const float* __restrict__ W1,
    __bf16* __restrict__ bpack)
{
  int unit = blockIdx.x * 256 + threadIdx.x;   // c*512 + t*64 + l
  int c  = unit >> 9;
  int t  = (unit >> 6) & 7;
  int l  = unit & 63;
  int q  = l >> 4;
  int np = l & 15;
  int n  = 16 * t + np;
  int kk = (c & 127) * 32 + q * 8;
  const float* W = (c < 128) ? W0 : W1;
  const float* src = W + (size_t)kk * HID + n;

  bf16x8 hi, lo;
#pragma unroll
  for (int j = 0; j < 8; ++j) {
    float x = src[(size_t)j * HID];
    __bf16 h = (__bf16)x;
    hi[j] = h;
    lo[j] = (__bf16)(x - (float)h);
  }
  bf16x8* base = (bf16x8*)bpack + (size_t)c * 1024;
  base[t * 64 + l]       = hi;
  base[512 + t * 64 + l] = lo;
}

// ---------------------------------------------------------------------------
// Main GEMM: 512 blocks x 256 thr, barrier-free. block = (rowblk, kslice);
// 128 rows per block, 32 rows per wave. B frags register-loaded from L2.
// ---------------------------------------------------------------------------
__global__ __launch_bounds__(256, 2) void vq_main(
    const float* __restrict__ s0, const float* __restrict__ s1,
    const __bf16* __restrict__ bpack, float* __restrict__ partial)
{
  const int tid  = threadIdx.x;
  const int wave = tid >> 6;
  const int lane = tid & 63;
  const int q    = lane >> 4;
  const int np   = lane & 15;
  const int rowblk = blockIdx.x >> 1;
  const int ks     = blockIdx.x & 1;
  const int rowbase = rowblk * 128 + wave * 32;

  const float* A = ks ? s1 : s0;
  const float* arow0 = A + (size_t)(rowbase + np) * DIM + q * 8;       // rows rowbase..+15
  const float* arow1 = arow0 + (size_t)16 * DIM;                       // rows rowbase+16..+31
  const bf16x8* bbase = (const bf16x8*)(bpack) + (size_t)ks * NCHUNK_SL * 1024;

  floatx4 acc0[8], acc1[8];
#pragma unroll
  for (int t = 0; t < 8; ++t) {
    acc0[t] = (floatx4){0.f, 0.f, 0.f, 0.f};
    acc1[t] = (floatx4){0.f, 0.f, 0.f, 0.f};
  }

  floatx4 araw[4];      // current-chunk A raw fp32 (reloaded with next chunk after convert)
  bf16x8  H0[8];        // B half-chunk buffer: t=0..3  [0..3]=hi, [4..7]=lo
  bf16x8  H1[8];        // B half-chunk buffer: t=4..7  [0..3]=hi, [4..7]=lo

  // ---- prologue: chunk 0 ----
  {
    const floatx4* p0 = (const floatx4*)arow0;
    const floatx4* p1 = (const floatx4*)arow1;
    araw[0] = __builtin_nontemporal_load(p0);
    araw[1] = __builtin_nontemporal_load(p0 + 1);
    araw[2] = __builtin_nontemporal_load(p1);
    araw[3] = __builtin_nontemporal_load(p1 + 1);
    const bf16x8* cb = bbase;
#pragma unroll
    for (int t = 0; t < 4; ++t) {
      H0[t]     = cb[t * 64 + lane];
      H0[4 + t] = cb[512 + t * 64 + lane];
      H1[t]     = cb[(4 + t) * 64 + lane];
      H1[4 + t] = cb[512 + (4 + t) * 64 + lane];
    }
  }

  for (int c = 0; c < NCHUNK_SL; ++c) {
    // convert current chunk A -> hi/lo bf16 fragments (frees araw)
    bf16x8 ahi0, alo0, ahi1, alo1;
#pragma unroll
    for (int h = 0; h < 2; ++h)
#pragma unroll
      for (int e = 0; e < 4; ++e) {
        float x0 = araw[h][e];
        __bf16 h0 = (__bf16)x0;
        ahi0[h * 4 + e] = h0;
        alo0[h * 4 + e] = (__bf16)(x0 - (float)h0);
        float x1 = araw[2 + h][e];
        __bf16 h1 = (__bf16)x1;
        ahi1[h * 4 + e] = h1;
        alo1[h * 4 + e] = (__bf16)(x1 - (float)h1);
      }

    const int cn = (c + 1) & (NCHUNK_SL - 1);   // wraps on last iter: harmless reload of chunk 0

    // prefetch next-chunk A (in flight across this whole chunk's MFMAs)
    {
      const floatx4* p0 = (const floatx4*)(arow0 + cn * 32);
      const floatx4* p1 = (const floatx4*)(arow1 + cn * 32);
      araw[0] = __builtin_nontemporal_load(p0);
      araw[1] = __builtin_nontemporal_load(p0 + 1);
      araw[2] = __builtin_nontemporal_load(p1);
      araw[3] = __builtin_nontemporal_load(p1 + 1);
    }
    const bf16x8* cb = bbase + (size_t)cn * 1024;

    // ---- first half: t = 0..3 from H0 ----
#pragma unroll
    for (int t = 0; t < 4; ++t) {
      bf16x8 bh = H0[t], bl = H0[4 + t];
      acc0[t] = __builtin_amdgcn_mfma_f32_16x16x32_bf16(ahi0, bh, acc0[t], 0, 0, 0);
      acc0[t] = __builtin_amdgcn_mfma_f32_16x16x32_bf16(alo0, bh, acc0[t], 0, 0, 0);
      acc0[t] = __builtin_amdgcn_mfma_f32_16x16x32_bf16(ahi0, bl, acc0[t], 0, 0, 0);
      acc1[t] = __builtin_amdgcn_mfma_f32_16x16x32_bf16(ahi1, bh, acc1[t], 0, 0, 0);
      acc1[t] = __builtin_amdgcn_mfma_f32_16x16x32_bf16(alo1, bh, acc1[t], 0, 0, 0);
      acc1[t] = __builtin_amdgcn_mfma_f32_16x16x32_bf16(ahi1, bl, acc1[t], 0, 0, 0);
    }
    // prefetch next-chunk first half into H0 (in flight across second half)
#pragma unroll
    for (int t = 0; t < 4; ++t) {
      H0[t]     = cb[t * 64 + lane];
      H0[4 + t] = cb[512 + t * 64 + lane];
    }

    // ---- second half: t = 4..7 from H1 ----
#pragma unroll
    for (int t = 0; t < 4; ++t) {
      bf16x8 bh = H1[t], bl = H1[4 + t];
      acc0[4 + t] = __builtin_amdgcn_mfma_f32_16x16x32_bf16(ahi0, bh, acc0[4 + t], 0, 0, 0);
      acc0[4 + t] = __builtin_amdgcn_mfma_f32_16x16x32_bf16(alo0, bh, acc0[4 + t], 0, 0, 0);
      acc0[4 + t] = __builtin_amdgcn_mfma_f32_16x16x32_bf16(ahi0, bl, acc0[4 + t], 0, 0, 0);
      acc1[4 + t] = __builtin_amdgcn_mfma_f32_16x16x32_bf16(ahi1, bh, acc1[4 + t], 0, 0, 0);
      acc1[4 + t] = __builtin_amdgcn_mfma_f32_16x16x32_bf16(alo1, bh, acc1[4 + t], 0, 0, 0);
      acc1[4 + t] = __builtin_amdgcn_mfma_f32_16x16x32_bf16(ahi1, bl, acc1[4 + t], 0, 0, 0);
    }
    // prefetch next-chunk second half into H1 (in flight across next iter's first half)
#pragma unroll
    for (int t = 0; t < 4; ++t) {
      H1[t]     = cb[(4 + t) * 64 + lane];
      H1[4 + t] = cb[512 + (4 + t) * 64 + lane];
    }
  }

  // store fp32 partial: partial[ks][row][col]; nontemporal (consumed by epi,
  // keep bpack L2-resident)
  float* pbase = partial + (size_t)ks * NROWS * HID;
#pragma unroll
  for (int r = 0; r < 4; ++r) {
    int row0 = rowbase + q * 4 + r;
    float* dst0 = pbase + (size_t)row0 * HID + np;
    float* dst1 = dst0 + (size_t)16 * HID;
#pragma unroll
    for (int t = 0; t < 8; ++t) {
      __builtin_nontemporal_store(acc0[t][r], dst0 + t * 16);
      __builtin_nontemporal_store(acc1[t][r], dst1 + t * 16);
    }
  }
}

// ---------------------------------------------------------------------------
// Epilogue: sum partials + bias + relu + flat = x@Wf + bf, VQ, hist.
// One row per thread. 128 blocks x 256 thr. (unchanged)
// ---------------------------------------------------------------------------
__global__ __launch_bounds__(256) void vq_epi(
    const float* __restrict__ partial,
    const float* __restrict__ b0, const float* __restrict__ b1,
    const float* __restrict__ Wf, const float* __restrict__ bf_p,
    const float* __restrict__ cb,
    float* __restrict__ out, int* __restrict__ hist)
{
  __shared__ float sWf[HID * 4];
  __shared__ float sB[HID];
  __shared__ float sCb[NCODE * 4];
  __shared__ int   sH[NCODE];

  int tid = threadIdx.x;
  for (int i = tid; i < HID * 4; i += 256) sWf[i] = Wf[i];
  for (int i = tid; i < HID; i += 256)     sB[i] = b0[i] + b1[i];
  for (int i = tid; i < NCODE * 4; i += 256) sCb[i] = cb[i];
  if (tid < NCODE) sH[tid] = 0;
  __syncthreads();

  int row = blockIdx.x * 256 + tid;
  const float* p0 = partial + (size_t)row * HID;
  const float* p1 = partial + ((size_t)NROWS + row) * HID;

  float f0 = 0.f, f1 = 0.f, f2 = 0.f, f3 = 0.f;
#pragma unroll 4
  for (int c4 = 0; c4 < HID / 4; ++c4) {
    floatx4 x0 = *(const floatx4*)(p0 + c4 * 4);
    floatx4 x1 = *(const floatx4*)(p1 + c4 * 4);
#pragma unroll
    for (int j = 0; j < 4; ++j) {
      int col = c4 * 4 + j;
      float x = fmaxf(x0[j] + x1[j] + sB[col], 0.f);
      f0 = fmaf(x, sWf[col * 4 + 0], f0);
      f1 = fmaf(x, sWf[col * 4 + 1], f1);
      f2 = fmaf(x, sWf[col * 4 + 2], f2);
      f3 = fmaf(x, sWf[col * 4 + 3], f3);
    }
  }
  f0 += bf_p[0]; f1 += bf_p[1]; f2 += bf_p[2]; f3 += bf_p[3];

  // VQ: reference formula, first-min-wins
  float fsq = f0 * f0 + f1 * f1 + f2 * f2 + f3 * f3;
  int best = 0;
  float bestd = 3.4e38f;
  float bc0 = 0.f, bc1 = 0.f, bc2 = 0.f, bc3 = 0.f;
#pragma unroll
  for (int k = 0; k < NCODE; ++k) {
    float c0 = sCb[k * 4], c1 = sCb[k * 4 + 1], c2 = sCb[k * 4 + 2], c3 = sCb[k * 4 + 3];
    float csq = c0 * c0 + c1 * c1 + c2 * c2 + c3 * c3;
    float dot = f0 * c0 + f1 * c1 + f2 * c2 + f3 * c3;
    float d = fsq + csq - 2.f * dot;
    if (d < bestd) { bestd = d; best = k; bc0 = c0; bc1 = c1; bc2 = c2; bc3 = c3; }
  }
  *(floatx4*)(out + Z_OFF + (size_t)row * 4) = (floatx4){bc0, bc1, bc2, bc3};
  float d0 = bc0 - f0, d1 = bc1 - f1, d2 = bc2 - f2, d3 = bc3 - f3;
  out[LOSS_OFF + row] = 0.5f * (d0 * d0 + d1 * d1 + d2 * d2 + d3 * d3);
  out[IDX_OFF + row] = (float)best;

  atomicAdd(&sH[best], 1);
  __syncthreads();
  if (tid < NCODE) atomicAdd(&hist[tid], sH[tid]);
}

// ---------------------------------------------------------------------------
__global__ void vq_perp(const int* __restrict__ hist, float* __restrict__ out)
{
  if (threadIdx.x == 0 && blockIdx.x == 0) {
    float s = 0.f;
    for (int k = 0; k < NCODE; ++k) {
      float p = (float)hist[k] * (1.0f / (float)NROWS);
      s += p * logf(p + 1e-10f);
    }
    out[PERP_OFF] = expf(-s);
  }
}

// ---------------------------------------------------------------------------
extern "C" void kernel_launch(void* const* d_in, const int* in_sizes, int n_in,
                              void* d_out, int out_size, void* d_ws, size_t ws_size,
                              hipStream_t stream)
{
  const float* s0 = (const float*)d_in[0];
  const float* s1 = (const float*)d_in[1];
  const float* W0 = (const float*)d_in[2];
  const float* b0 = (const float*)d_in[3];
  const float* W1 = (const float*)d_in[4];
  const float* b1 = (const float*)d_in[5];
  const float* Wf = (const float*)d_in[6];
  const float* bf = (const float*)d_in[7];
  const float* cb = (const float*)d_in[8];
  float* out = (float*)d_out;

  int*    hist    = (int*)((char*)d_ws + HIST_OFF_B);
  __bf16* bpack   = (__bf16*)((char*)d_ws + BPACK_OFF_B);
  float*  partial = (float*)((char*)d_ws + PART_OFF_B);

  hipMemsetAsync(d_ws, 0, 256, stream);                         // zero histogram
  vq_prep_pack<<<512, 256, 0, stream>>>(W0, W1, bpack);
  vq_main<<<512, 256, 0, stream>>>(s0, s1, bpack, partial);
  vq_epi<<<NROWS / 256, 256, 0, stream>>>(partial, b0, b1, Wf, bf, cb, out, hist);
  vq_perp<<<1, 64, 0, stream>>>(hist, out);
}